// Round 15
// baseline (123.782 us; speedup 1.0000x reference)
//
#include <hip/hip_runtime.h>
#include <hip/hip_bf16.h>
#include <cstdint>

// Problem: B=32, S=1024, H_IN=1024, H=1024
// scores[b,s] = sum_h tanh( enc[b,s,:]·W1_enc[h,:] + hidden[b,:]·W1_hid[h,:] + b1[h] ) * W2[h]
// out[b,0,s] = softmax_s( mask ? -inf : scores )    (b2 is softmax-shift-invariant)
//
// Round 15 (4 launches): FLAT GEMM — no LDS, no barriers. prep_k packs W1_enc into
// MFMA-fragment order (Wfrag[rt][kt][kk][lane], 16B/lane); conv_k gathers+converts
// compacted enc rows into the same fragment order (encF[b][rt][kt][kk][lane]).
// gemm_flat loads fragments register-direct (coalesced 1KB/wave dwordx4, L2-hot),
// 8 MFMA per 6 loads, zero sync. Epilogue/softmax unchanged (r13-proven).
//
// Fragment layout (both operands, element-verified): tile key (rt=row>>4, kt, kk),
// lane (llo=row&15, lhi): holds M[rt*16+llo][kt*64+kk*32+lhi*8 .. +7].
// addr16B = (rt*32 + kt*2 + kk)*64 + lhi*16 + llo   (+ b*64*2048 for encF)

typedef short  s16x8 __attribute__((ext_vector_type(8)));
typedef float  f32x4 __attribute__((ext_vector_type(4)));
typedef unsigned int u32;
typedef unsigned short u16;
typedef unsigned long long u64;

__device__ static inline u32 f2bf(float f) {            // f32 -> bf16 (RNE)
    u32 u = __float_as_uint(f);
    return (u + 0x7fffu + ((u >> 16) & 1u)) >> 16;
}
__device__ static inline u32 pk2(float a, float b) {
    return f2bf(a) | (f2bf(b) << 16);
}

// ---------------- prep: pack W1_enc (FRAGMENT order) + hv + mask compaction + zero scores ----------------
__global__ __launch_bounds__(256) void prep_k(const float* __restrict__ W1,
                                              const float* __restrict__ hidden,
                                              const float* __restrict__ b1,
                                              const void*  __restrict__ maskv,
                                              u16*   __restrict__ Wfrag,
                                              float* __restrict__ hv,
                                              int*   __restrict__ sidx,
                                              int*   __restrict__ cnt,
                                              float* __restrict__ scores) {
    const int bx = blockIdx.x, t = threadIdx.x;
    const int wid = t >> 6, lane = t & 63;
    __shared__ int sflag[4];

    if (bx < 512) {
        // pack W1_enc to bf16 in fragment order; thread i produces out 16B-chunk i
        const int i = bx * 256 + t;                    // 0..131071
        const int llo = i & 15, lhi = (i >> 4) & 3;
        const int kk = (i >> 6) & 1, kt = (i >> 7) & 15, rt = i >> 11;   // rt 0..63
        const int n = rt * 16 + llo;
        const int kb = kt * 64 + kk * 32 + lhi * 8;
        const float4 v0 = *(const float4*)(W1 + (size_t)n * 2048 + kb);
        const float4 v1 = *(const float4*)(W1 + (size_t)n * 2048 + kb + 4);
        uint4 o; o.x = pk2(v0.x, v0.y); o.y = pk2(v0.z, v0.w);
        o.z = pk2(v1.x, v1.y); o.w = pk2(v1.z, v1.w);
        *(uint4*)(Wfrag + (size_t)i * 8) = o;
    } else if (bx < 768) {
        // hv[b][h] = hidden[b,:]·W1_hid[h,:] + b1[h]
        const int h = (bx - 512) * 4 + wid;
        const float4* wrow = (const float4*)(W1 + (size_t)h * 2048 + 1024);
        float4 w[4];
#pragma unroll
        for (int q = 0; q < 4; q++) w[q] = wrow[lane + 64 * q];
        for (int b = 0; b < 32; b++) {
            const float4* hb = (const float4*)(hidden + (size_t)b * 1024);
            float p = 0.f;
#pragma unroll
            for (int q = 0; q < 4; q++) {
                float4 x = hb[lane + 64 * q];
                p = fmaf(w[q].x, x.x, fmaf(w[q].y, x.y, fmaf(w[q].z, x.z, fmaf(w[q].w, x.w, p))));
            }
#pragma unroll
            for (int off = 1; off < 64; off <<= 1) p += __shfl_xor(p, off);
            if (lane == 0) hv[(size_t)b * 1024 + h] = p + b1[h];
        }
    } else if (bx < 776) {
        // mask dtype detect + per-batch stable compaction of unmasked s
        const u32* mw = (const u32*)maskv;
        int f = 0;
#pragma unroll
        for (int j = 0; j < 32; j++) f |= (mw[t * 32 + j] > 1u) ? 1 : 0;
        const int anyf = __any(f);
        if (lane == 0) sflag[wid] = anyf;
        __syncthreads();
        const int bytemode = sflag[0] | sflag[1] | sflag[2] | sflag[3];

        const int b = (bx - 768) * 4 + wid;
        int base = 0;
        for (int c = 0; c < 16; c++) {
            const int s = c * 64 + lane;
            int m;
            if (bytemode) m = ((const unsigned char*)maskv)[(size_t)b * 1024 + s];
            else          m = ((const int*)maskv)[(size_t)b * 1024 + s];
            const u64 bal = __ballot(m == 0);
            if (m == 0) {
                const int off = (int)__popcll(bal & ((1ull << lane) - 1ull));
                sidx[(size_t)b * 1024 + base + off] = s;
            }
            base += (int)__popcll(bal);
        }
        if (lane == 0) cnt[b] = base;
        for (int j = base + lane; j < 1024; j += 64) sidx[(size_t)b * 1024 + j] = 0;
    } else {
        // zero scores
        const int i = (bx - 776) * 256 + t;
        ((float4*)scores)[i] = make_float4(0.f, 0.f, 0.f, 0.f);
    }
}

// ---------------- gather-convert compacted enc rows to bf16, FRAGMENT order ----------------
// 8192 blocks, XCD-aligned (batches [4X,4X+4) on XCD X). 4 rows per block,
// 512 (row,chunk16B) pairs over 256 threads (2 each).
__global__ __launch_bounds__(256) void conv_k(const float* __restrict__ enc,
                                              const int* __restrict__ sidx,
                                              const int* __restrict__ cnt,
                                              u16* __restrict__ encF) {
    const int bid = blockIdx.x, t = threadIdx.x;
    const int xcd = bid & 7, w = bid >> 3;             // w 0..1023
    const int b = xcd * 4 + (w >> 8);                  // batches 4X..4X+3 on XCD X
    const int j0 = (w & 255) * 4;
    const int c = cnt[b];
    if (j0 >= ((c + 127) & ~127)) return;              // covers all gemm row-tiles
#pragma unroll
    for (int p = 0; p < 2; p++) {
        const int q = t + p * 256;                     // 0..511
        const int jl = q >> 7, c8 = q & 127;           // row-in-block, out 16B chunk
        const int j = j0 + jl;
        const int s = (j < c) ? sidx[(size_t)b * 1024 + j] : 0;
        const float* src = enc + ((size_t)s * 32 + b) * 1024 + c8 * 8;
        const float4 v0 = *(const float4*)src;
        const float4 v1 = *(const float4*)(src + 4);
        const int rt = j >> 4, llo = j & 15;
        const int kt = c8 >> 3, kk = (c8 >> 2) & 1, lhi = c8 & 3;
        const size_t a16 = (((size_t)b * 64 + rt) * 32 + kt * 2 + kk) * 64 + lhi * 16 + llo;
        uint4 o; o.x = pk2(v0.x, v0.y); o.y = pk2(v0.z, v0.w);
        o.z = pk2(v1.x, v1.y); o.w = pk2(v1.z, v1.w);
        *(uint4*)(encF + a16 * 8) = o;
    }
}

// ---------------- FLAT GEMM: no LDS, no barriers; fragment loads -> MFMA ----------------
// 256 thr = 4 waves (wr 0..1 x wc 0..1); per-wave out 32x64 (acc[2][4]).
// Per (kt,kk): 2 A-frag + 4 B-frag coalesced dwordx4 loads (L2-hot), 8 MFMA.
__global__ __launch_bounds__(256, 4) void gemm_flat(
    const u16* __restrict__ encF,       // [32][64][32][64] frags
    const u16* __restrict__ Wfrag,      // [64][32][64] frags
    const int* __restrict__ sidx,
    const int* __restrict__ cnt,
    const float* __restrict__ hv,
    const float* __restrict__ W2,
    float*      __restrict__ scores)    // [32][1024] f32, pre-zeroed, atomics
{
    const int tid = threadIdx.x;
    const int bid = blockIdx.x;         // 4096 blocks
    // XCD map: batches [4X,4X+4) on XCD X (conv-aligned); 8 nt per (b,mt) strip
    const int xcd = bid & 7, idx = bid >> 3;           // idx 0..511
    const int strip = xcd * 64 + (idx >> 3);           // 0..511 = b*16+mt
    const int nt = idx & 7;
    const int b = strip >> 4, mt = strip & 15;
    const int c = cnt[b];
    if (mt * 64 >= c) return;

    const int wid = tid >> 6, lane = tid & 63;
    const int wr = wid >> 1, wc = wid & 1;
    const int lhi = lane >> 4, llo = lane & 15;

    // fragment bases (u16 units); frag(f, kt, kk) = base + (f*32 + kt*2 + kk)*512
    const u16* Abase = encF + (((size_t)b * 64 + mt * 4 + wr * 2) * 32 * 64 + lane) * 8;
    const u16* Bbase = Wfrag + (((size_t)nt * 8 + wc * 4) * 32 * 64 + lane) * 8;

    f32x4 acc[2][4] = {};

#pragma unroll 2
    for (int kt = 0; kt < 16; kt++) {
#pragma unroll
        for (int kk = 0; kk < 2; kk++) {
            const int off = (kt * 2 + kk) * 512;
            s16x8 af[2], bf[4];
#pragma unroll
            for (int fi = 0; fi < 2; fi++)
                af[fi] = *(const s16x8*)(Abase + off + fi * 16384);   // fi*32*512
#pragma unroll
            for (int fj = 0; fj < 4; fj++)
                bf[fj] = *(const s16x8*)(Bbase + off + fj * 16384);
#pragma unroll
            for (int fi = 0; fi < 2; fi++)
#pragma unroll
                for (int fj = 0; fj < 4; fj++)
                    acc[fi][fj] = __builtin_amdgcn_mfma_f32_16x16x32_bf16(
                        af[fi], bf[fj], acc[fi][fj], 0, 0, 0);
        }
    }

    // epilogue: tanh(acc + hv) · w2, reduce over this wave's 64 n-cols, scatter-atomic
    const float* hvb = hv + (size_t)b * 1024;
    float hvv[4], w2v[4];
#pragma unroll
    for (int fj = 0; fj < 4; fj++) {
        const int n = nt * 128 + wc * 64 + fj * 16 + llo;
        hvv[fj] = hvb[n];
        w2v[fj] = W2[n];
    }
#pragma unroll
    for (int fi = 0; fi < 2; fi++) {
#pragma unroll
        for (int r = 0; r < 4; r++) {
            float sum = 0.f;
#pragma unroll
            for (int fj = 0; fj < 4; fj++) {
                const float x = acc[fi][fj][r] + hvv[fj];
                const float e = __expf(2.f * x);
                const float t = 1.f - 2.f / (e + 1.f);   // tanh(x)
                sum = fmaf(t, w2v[fj], sum);
            }
            sum += __shfl_xor(sum, 1);
            sum += __shfl_xor(sum, 2);
            sum += __shfl_xor(sum, 4);
            sum += __shfl_xor(sum, 8);
            if (llo == 0) {
                const int j = mt * 64 + wr * 32 + fi * 16 + lhi * 4 + r;
                if (j < c) {
                    const int s = sidx[(size_t)b * 1024 + j];
                    atomicAdd(&scores[(size_t)b * 1024 + s], sum);
                }
            }
        }
    }
}

// ---------------- masked softmax per row b, mask dtype auto-detected ----------------
__global__ __launch_bounds__(256) void softmax_k(const float* __restrict__ scores,
                                                 const void* __restrict__ maskv,
                                                 float* __restrict__ out) {
    const int b = blockIdx.x, t = threadIdx.x;
    const int wid = t >> 6, lane = t & 63;
    const u32* mw = (const u32*)maskv;
    int f = 0;
#pragma unroll
    for (int j = 0; j < 32; j++) f |= (mw[t * 32 + j] > 1u) ? 1 : 0;
    __shared__ int sflag[4];
    const int anyf = __any(f);
    if (lane == 0) sflag[wid] = anyf;
    __syncthreads();
    const int bytemode = sflag[0] | sflag[1] | sflag[2] | sflag[3];

    int m0, m1, m2, m3;
    if (bytemode) {
        const uchar4 mk = ((const uchar4*)((const unsigned char*)maskv + (size_t)b * 1024))[t];
        m0 = mk.x; m1 = mk.y; m2 = mk.z; m3 = mk.w;
    } else {
        const int4 mk = ((const int4*)((const int*)maskv + (size_t)b * 1024))[t];
        m0 = mk.x; m1 = mk.y; m2 = mk.z; m3 = mk.w;
    }
    const float4 sc = ((const float4*)(scores + (size_t)b * 1024))[t];
    const float v0 = m0 ? -1e30f : sc.x;
    const float v1 = m1 ? -1e30f : sc.y;
    const float v2 = m2 ? -1e30f : sc.z;
    const float v3 = m3 ? -1e30f : sc.w;
    float mx = fmaxf(fmaxf(v0, v1), fmaxf(v2, v3));
#pragma unroll
    for (int off = 1; off < 64; off <<= 1) mx = fmaxf(mx, __shfl_xor(mx, off));
    __shared__ float redm[4], reds[4];
    if (lane == 0) redm[wid] = mx;
    __syncthreads();
    mx = fmaxf(fmaxf(redm[0], redm[1]), fmaxf(redm[2], redm[3]));
    const float e0 = m0 ? 0.f : __expf(v0 - mx);
    const float e1 = m1 ? 0.f : __expf(v1 - mx);
    const float e2 = m2 ? 0.f : __expf(v2 - mx);
    const float e3 = m3 ? 0.f : __expf(v3 - mx);
    float s = e0 + e1 + e2 + e3;
#pragma unroll
    for (int off = 1; off < 64; off <<= 1) s += __shfl_xor(s, off);
    if (lane == 0) reds[wid] = s;
    __syncthreads();
    s = reds[0] + reds[1] + reds[2] + reds[3];
    const float inv = 1.f / s;
    float4 o; o.x = e0 * inv; o.y = e1 * inv; o.z = e2 * inv; o.w = e3 * inv;
    ((float4*)(out + (size_t)b * 1024))[t] = o;
}

extern "C" void kernel_launch(void* const* d_in, const int* in_sizes, int n_in,
                              void* d_out, int out_size, void* d_ws, size_t ws_size,
                              hipStream_t stream) {
    const float* hidden = (const float*)d_in[0];
    const float* enc    = (const float*)d_in[1];           // (S,B,H_IN) f32
    const void*  mask   = d_in[2];
    const float* W1 = (const float*)d_in[3];               // (H, H_IN+H) f32
    const float* b1 = (const float*)d_in[4];
    const float* W2 = (const float*)d_in[5];
    float* out = (float*)d_out;

    char* ws = (char*)d_ws;
    float* ws_scores = (float*)ws;                          // 128 KB
    float* ws_hv     = (float*)(ws + (128u << 10));         // 128 KB
    u16*   ws_Wb     = (u16*)(ws + (256u << 10));           // 2 MB  (fragment order)
    int*   ws_cnt    = (int*)(ws + (2304u << 10));          // 128 B
    int*   ws_sidx   = (int*)(ws + (2432u << 10));          // 128 KB
    u16*   ws_encF   = (u16*)(ws + (4096u << 10));          // 64 MB (fragment order)

    prep_k<<<808, 256, 0, stream>>>(W1, hidden, b1, mask, ws_Wb, ws_hv, ws_sidx, ws_cnt, ws_scores);
    conv_k<<<8192, 256, 0, stream>>>(enc, ws_sidx, ws_cnt, ws_encF);
    gemm_flat<<<4096, 256, 0, stream>>>(ws_encF, ws_Wb, ws_sidx, ws_cnt, ws_hv, W2, ws_scores);
    softmax_k<<<32, 256, 0, stream>>>(ws_scores, mask, out);
}

// Round 16
// 118.031 us; speedup vs baseline: 1.0487x; 1.0487x over previous
//
#include <hip/hip_runtime.h>
#include <hip/hip_bf16.h>
#include <cstdint>

// Problem: B=32, S=1024, H_IN=1024, H=1024
// scores[b,s] = sum_h tanh( enc[b,s,:]·W1_enc[h,:] + hidden[b,:]·W1_hid[h,:] + b1[h] ) * W2[h]
// out[b,0,s] = softmax_s( mask ? -inf : scores )    (b2 is softmax-shift-invariant)
//
// Round 16 (4 launches): HYBRID gemm — A register-direct from fragment-ordered encF
// (r15 conv, proven), B LDS-staged from pre-swizzled Wb (r13 prep, proven).
// Cuts LDS traffic 72->48 KB/K-step and LDS size 24->16 KB (up to 8 blk/CU).
// BM=64 BN=128 BK=64, 4 waves; epilogue/softmax r13-exact.

#define BK 64
#define NKT 16

typedef short  s16x8 __attribute__((ext_vector_type(8)));
typedef float  f32x4 __attribute__((ext_vector_type(4)));
typedef unsigned int u32;
typedef unsigned short u16;
typedef unsigned long long u64;

__device__ static inline u32 f2bf(float f) {            // f32 -> bf16 (RNE)
    u32 u = __float_as_uint(f);
    return (u + 0x7fffu + ((u >> 16) & 1u)) >> 16;
}
__device__ static inline u32 pk2(float a, float b) {
    return f2bf(a) | (f2bf(b) << 16);
}

__device__ static inline void gload_lds16(const void* g, void* l) {
    __builtin_amdgcn_global_load_lds(
        (const __attribute__((address_space(1))) u32*)g,
        (__attribute__((address_space(3))) u32*)l, 16, 0, 0);
}

// ---------------- prep: pack W1_enc (SWIZZLED, r13) + hv + mask compaction + zero scores ----------------
__global__ __launch_bounds__(256) void prep_k(const float* __restrict__ W1,
                                              const float* __restrict__ hidden,
                                              const float* __restrict__ b1,
                                              const void*  __restrict__ maskv,
                                              u16*   __restrict__ Wb,
                                              float* __restrict__ hv,
                                              int*   __restrict__ sidx,
                                              int*   __restrict__ cnt,
                                              float* __restrict__ scores) {
    const int bx = blockIdx.x, t = threadIdx.x;
    const int wid = t >> 6, lane = t & 63;
    __shared__ int sflag[4];

    if (bx < 512) {
        // pack W1_enc to bf16, swizzled: chunk gc -> (gc&~7)|((gc&7)^(n&7))
        const int i = bx * 256 + t;                    // 16B-out-chunk id, 0..131071
        const int n = i >> 7, gc = i & 127;
        const int p = (gc & ~7) | ((gc & 7) ^ (n & 7));
        const float4 v0 = *(const float4*)(W1 + (size_t)n * 2048 + gc * 8);
        const float4 v1 = *(const float4*)(W1 + (size_t)n * 2048 + gc * 8 + 4);
        uint4 o; o.x = pk2(v0.x, v0.y); o.y = pk2(v0.z, v0.w);
        o.z = pk2(v1.x, v1.y); o.w = pk2(v1.z, v1.w);
        *(uint4*)(Wb + (size_t)n * 1024 + p * 8) = o;
    } else if (bx < 768) {
        // hv[b][h] = hidden[b,:]·W1_hid[h,:] + b1[h]
        const int h = (bx - 512) * 4 + wid;
        const float4* wrow = (const float4*)(W1 + (size_t)h * 2048 + 1024);
        float4 w[4];
#pragma unroll
        for (int q = 0; q < 4; q++) w[q] = wrow[lane + 64 * q];
        for (int b = 0; b < 32; b++) {
            const float4* hb = (const float4*)(hidden + (size_t)b * 1024);
            float p = 0.f;
#pragma unroll
            for (int q = 0; q < 4; q++) {
                float4 x = hb[lane + 64 * q];
                p = fmaf(w[q].x, x.x, fmaf(w[q].y, x.y, fmaf(w[q].z, x.z, fmaf(w[q].w, x.w, p))));
            }
#pragma unroll
            for (int off = 1; off < 64; off <<= 1) p += __shfl_xor(p, off);
            if (lane == 0) hv[(size_t)b * 1024 + h] = p + b1[h];
        }
    } else if (bx < 776) {
        // mask dtype detect + per-batch stable compaction of unmasked s
        const u32* mw = (const u32*)maskv;
        int f = 0;
#pragma unroll
        for (int j = 0; j < 32; j++) f |= (mw[t * 32 + j] > 1u) ? 1 : 0;
        const int anyf = __any(f);
        if (lane == 0) sflag[wid] = anyf;
        __syncthreads();
        const int bytemode = sflag[0] | sflag[1] | sflag[2] | sflag[3];

        const int b = (bx - 768) * 4 + wid;
        int base = 0;
        for (int c = 0; c < 16; c++) {
            const int s = c * 64 + lane;
            int m;
            if (bytemode) m = ((const unsigned char*)maskv)[(size_t)b * 1024 + s];
            else          m = ((const int*)maskv)[(size_t)b * 1024 + s];
            const u64 bal = __ballot(m == 0);
            if (m == 0) {
                const int off = (int)__popcll(bal & ((1ull << lane) - 1ull));
                sidx[(size_t)b * 1024 + base + off] = s;
            }
            base += (int)__popcll(bal);
        }
        if (lane == 0) cnt[b] = base;
        for (int j = base + lane; j < 1024; j += 64) sidx[(size_t)b * 1024 + j] = 0;
    } else {
        // zero scores
        const int i = (bx - 776) * 256 + t;
        ((float4*)scores)[i] = make_float4(0.f, 0.f, 0.f, 0.f);
    }
}

// ---------------- gather-convert compacted enc rows to bf16, FRAGMENT order (r15) ----------------
// 8192 blocks, XCD-aligned (batches [4X,4X+4) on XCD X). 4 rows per block.
// Fragment layout: addr16B = ((b*64+rt)*32 + kt*2 + kk)*64 + lhi*16 + llo
// holds enc_row[rt*16+llo][kt*64+kk*32+lhi*8 .. +7].
__global__ __launch_bounds__(256) void conv_k(const float* __restrict__ enc,
                                              const int* __restrict__ sidx,
                                              const int* __restrict__ cnt,
                                              u16* __restrict__ encF) {
    const int bid = blockIdx.x, t = threadIdx.x;
    const int xcd = bid & 7, w = bid >> 3;             // w 0..1023
    const int b = xcd * 4 + (w >> 8);                  // batches 4X..4X+3 on XCD X
    const int j0 = (w & 255) * 4;
    const int c = cnt[b];
    if (j0 >= ((c + 127) & ~127)) return;              // covers all gemm row-tiles
#pragma unroll
    for (int p = 0; p < 2; p++) {
        const int q = t + p * 256;                     // 0..511
        const int jl = q >> 7, c8 = q & 127;           // row-in-block, out 16B chunk
        const int j = j0 + jl;
        const int s = (j < c) ? sidx[(size_t)b * 1024 + j] : 0;
        const float* src = enc + ((size_t)s * 32 + b) * 1024 + c8 * 8;
        const float4 v0 = *(const float4*)src;
        const float4 v1 = *(const float4*)(src + 4);
        const int rt = j >> 4, llo = j & 15;
        const int kt = c8 >> 3, kk = (c8 >> 2) & 1, lhi = c8 & 3;
        const size_t a16 = (((size_t)b * 64 + rt) * 32 + kt * 2 + kk) * 64 + lhi * 16 + llo;
        uint4 o; o.x = pk2(v0.x, v0.y); o.y = pk2(v0.z, v0.w);
        o.z = pk2(v1.x, v1.y); o.w = pk2(v1.z, v1.w);
        *(uint4*)(encF + a16 * 8) = o;
    }
}

// ---------------- HYBRID GEMM: A reg-direct fragments, B swizzled LDS ----------------
// 256 thr = 4 waves (wr 0..1 x wc 0..1); per-wave out 32x64 (acc[2][4]).
__global__ __launch_bounds__(256, 6) void gemm_h(
    const u16* __restrict__ encF,       // [32][64][32][64] frags
    const u16* __restrict__ Wb,         // [1024][1024] bf16, swizzled rows
    const int* __restrict__ sidx,
    const int* __restrict__ cnt,
    const float* __restrict__ hv,
    const float* __restrict__ W2,
    float*      __restrict__ scores)    // [32][1024] f32, pre-zeroed, atomics
{
    __shared__ u16 Bs[128 * BK];        // 16 KB only

    const int tid = threadIdx.x;
    const int bid = blockIdx.x;         // 4096 blocks
    // XCD map (bijective): batches [4X,4X+4) on XCD X (conv-aligned); 8 nt per (b,mt)
    const int xcd = bid & 7, idx = bid >> 3;           // idx 0..511
    const int strip = xcd * 64 + (idx >> 3);           // 0..511 = b*16+mt
    const int nt = idx & 7;
    const int b = strip >> 4, mt = strip & 15;
    const int c = cnt[b];
    if (mt * 64 >= c) return;

    const int wid = tid >> 6, lane = tid & 63;
    const int wr = wid >> 1, wc = wid & 1;
    const int lhi = lane >> 4, llo = lane & 15;

    // A fragment base (r15-proven): frag(fi, kt, kk) = Abase + (kt*2+kk)*512 + fi*16384
    const u16* Abase = encF + (((size_t)b * 64 + mt * 4 + wr * 2) * 32 * 64 + lane) * 8;

    // B staging (r13-exact): chunk idx -> row = chunk>>3, c16 = chunk&7; LINEAR
    const int srow = tid >> 3, sc16 = tid & 7;         // srow 0..31
    const u16* bsrc = Wb + ((size_t)(nt * 128) + srow) * 1024 + sc16 * 8;

    f32x4 acc[2][4] = {};

    for (int kt = 0; kt < NKT; kt++) {
        const size_t ko = (size_t)kt * 64;
#pragma unroll
        for (int j = 0; j < 4; j++)                    // B: 1024 chunks
            gload_lds16(bsrc + ko + (size_t)j * 32 * 1024, &Bs[(j * 256 + tid) * 8]);
        __syncthreads();
#pragma unroll
        for (int kk = 0; kk < 2; kk++) {
            const int aoff = (kt * 2 + kk) * 512;
            s16x8 af[2], bfr[4];
#pragma unroll
            for (int fi = 0; fi < 2; fi++)
                af[fi] = *(const s16x8*)(Abase + aoff + fi * 16384);
#pragma unroll
            for (int f = 0; f < 4; f++) {
                const int row = wc * 64 + f * 16 + llo;
                const int ph = (kk * 4 + lhi) ^ (llo & 7);
                bfr[f] = *(const s16x8*)&Bs[row * BK + ph * 8];
            }
#pragma unroll
            for (int fi = 0; fi < 2; fi++)
#pragma unroll
                for (int fj = 0; fj < 4; fj++)
                    acc[fi][fj] = __builtin_amdgcn_mfma_f32_16x16x32_bf16(
                        af[fi], bfr[fj], acc[fi][fj], 0, 0, 0);
        }
        __syncthreads();
    }

    // epilogue: tanh(acc + hv) · w2, reduce over this wave's 64 n-cols, scatter-atomic
    const float* hvb = hv + (size_t)b * 1024;
    float hvv[4], w2v[4];
#pragma unroll
    for (int fj = 0; fj < 4; fj++) {
        const int n = nt * 128 + wc * 64 + fj * 16 + llo;
        hvv[fj] = hvb[n];
        w2v[fj] = W2[n];
    }
#pragma unroll
    for (int fi = 0; fi < 2; fi++) {
#pragma unroll
        for (int r = 0; r < 4; r++) {
            float sum = 0.f;
#pragma unroll
            for (int fj = 0; fj < 4; fj++) {
                const float x = acc[fi][fj][r] + hvv[fj];
                const float e = __expf(2.f * x);
                const float t = 1.f - 2.f / (e + 1.f);   // tanh(x)
                sum = fmaf(t, w2v[fj], sum);
            }
            sum += __shfl_xor(sum, 1);
            sum += __shfl_xor(sum, 2);
            sum += __shfl_xor(sum, 4);
            sum += __shfl_xor(sum, 8);
            if (llo == 0) {
                const int j = mt * 64 + wr * 32 + fi * 16 + lhi * 4 + r;
                if (j < c) {
                    const int s = sidx[(size_t)b * 1024 + j];
                    atomicAdd(&scores[(size_t)b * 1024 + s], sum);
                }
            }
        }
    }
}

// ---------------- masked softmax per row b, mask dtype auto-detected ----------------
__global__ __launch_bounds__(256) void softmax_k(const float* __restrict__ scores,
                                                 const void* __restrict__ maskv,
                                                 float* __restrict__ out) {
    const int b = blockIdx.x, t = threadIdx.x;
    const int wid = t >> 6, lane = t & 63;
    const u32* mw = (const u32*)maskv;
    int f = 0;
#pragma unroll
    for (int j = 0; j < 32; j++) f |= (mw[t * 32 + j] > 1u) ? 1 : 0;
    __shared__ int sflag[4];
    const int anyf = __any(f);
    if (lane == 0) sflag[wid] = anyf;
    __syncthreads();
    const int bytemode = sflag[0] | sflag[1] | sflag[2] | sflag[3];

    int m0, m1, m2, m3;
    if (bytemode) {
        const uchar4 mk = ((const uchar4*)((const unsigned char*)maskv + (size_t)b * 1024))[t];
        m0 = mk.x; m1 = mk.y; m2 = mk.z; m3 = mk.w;
    } else {
        const int4 mk = ((const int4*)((const int*)maskv + (size_t)b * 1024))[t];
        m0 = mk.x; m1 = mk.y; m2 = mk.z; m3 = mk.w;
    }
    const float4 sc = ((const float4*)(scores + (size_t)b * 1024))[t];
    const float v0 = m0 ? -1e30f : sc.x;
    const float v1 = m1 ? -1e30f : sc.y;
    const float v2 = m2 ? -1e30f : sc.z;
    const float v3 = m3 ? -1e30f : sc.w;
    float mx = fmaxf(fmaxf(v0, v1), fmaxf(v2, v3));
#pragma unroll
    for (int off = 1; off < 64; off <<= 1) mx = fmaxf(mx, __shfl_xor(mx, off));
    __shared__ float redm[4], reds[4];
    if (lane == 0) redm[wid] = mx;
    __syncthreads();
    mx = fmaxf(fmaxf(redm[0], redm[1]), fmaxf(redm[2], redm[3]));
    const float e0 = m0 ? 0.f : __expf(v0 - mx);
    const float e1 = m1 ? 0.f : __expf(v1 - mx);
    const float e2 = m2 ? 0.f : __expf(v2 - mx);
    const float e3 = m3 ? 0.f : __expf(v3 - mx);
    float s = e0 + e1 + e2 + e3;
#pragma unroll
    for (int off = 1; off < 64; off <<= 1) s += __shfl_xor(s, off);
    if (lane == 0) reds[wid] = s;
    __syncthreads();
    s = reds[0] + reds[1] + reds[2] + reds[3];
    const float inv = 1.f / s;
    float4 o; o.x = e0 * inv; o.y = e1 * inv; o.z = e2 * inv; o.w = e3 * inv;
    ((float4*)(out + (size_t)b * 1024))[t] = o;
}

extern "C" void kernel_launch(void* const* d_in, const int* in_sizes, int n_in,
                              void* d_out, int out_size, void* d_ws, size_t ws_size,
                              hipStream_t stream) {
    const float* hidden = (const float*)d_in[0];
    const float* enc    = (const float*)d_in[1];           // (S,B,H_IN) f32
    const void*  mask   = d_in[2];
    const float* W1 = (const float*)d_in[3];               // (H, H_IN+H) f32
    const float* b1 = (const float*)d_in[4];
    const float* W2 = (const float*)d_in[5];
    float* out = (float*)d_out;

    char* ws = (char*)d_ws;
    float* ws_scores = (float*)ws;                          // 128 KB
    float* ws_hv     = (float*)(ws + (128u << 10));         // 128 KB
    u16*   ws_Wb     = (u16*)(ws + (256u << 10));           // 2 MB (swizzled)
    int*   ws_cnt    = (int*)(ws + (2304u << 10));          // 128 B
    int*   ws_sidx   = (int*)(ws + (2432u << 10));          // 128 KB
    u16*   ws_encF   = (u16*)(ws + (4096u << 10));          // 64 MB (fragment order)

    prep_k<<<808, 256, 0, stream>>>(W1, hidden, b1, mask, ws_Wb, ws_hv, ws_sidx, ws_cnt, ws_scores);
    conv_k<<<8192, 256, 0, stream>>>(enc, ws_sidx, ws_cnt, ws_encF);
    gemm_h<<<4096, 256, 0, stream>>>(ws_encF, ws_Wb, ws_sidx, ws_cnt, ws_hv, W2, ws_scores);
    softmax_k<<<32, 256, 0, stream>>>(ws_scores, mask, out);
}

// Round 17
// 108.596 us; speedup vs baseline: 1.1398x; 1.0869x over previous
//
#include <hip/hip_runtime.h>
#include <hip/hip_bf16.h>
#include <cstdint>

// Problem: B=32, S=1024, H_IN=1024, H=1024
// scores[b,s] = sum_h tanh( enc[b,s,:]·W1_enc[h,:] + hidden[b,:]·W1_hid[h,:] + b1[h] ) * W2[h]
// out[b,0,s] = softmax_s( mask ? -inf : scores )    (b2 is softmax-shift-invariant)
//
// Round 17 (4 launches): r13 pipeline; gemm geometry only changed to 512-thread
// 128x128 tile, 8 waves (4M x 2N), per-wave 32x64 (same fragment shape & swizzle
// as r13's proven gemm_s). 32 KB LDS -> wave-capped 4 blocks/CU = 32 waves/CU
// (FULL), ~1100 active blocks all co-resident (no tail); staging bytes/FLOP and
// barriers/FLOP halve vs r13. prep/conv/softmax byte-identical to r13.

#define BK 64
#define NKT 16

typedef short  s16x8 __attribute__((ext_vector_type(8)));
typedef float  f32x4 __attribute__((ext_vector_type(4)));
typedef unsigned int u32;
typedef unsigned short u16;
typedef unsigned long long u64;

__device__ static inline u32 f2bf(float f) {            // f32 -> bf16 (RNE)
    u32 u = __float_as_uint(f);
    return (u + 0x7fffu + ((u >> 16) & 1u)) >> 16;
}
__device__ static inline u32 pk2(float a, float b) {
    return f2bf(a) | (f2bf(b) << 16);
}

__device__ static inline void gload_lds16(const void* g, void* l) {
    __builtin_amdgcn_global_load_lds(
        (const __attribute__((address_space(1))) u32*)g,
        (__attribute__((address_space(3))) u32*)l, 16, 0, 0);
}

// ---------------- prep: pack W1_enc (SWIZZLED) + hv + mask compaction + zero scores ----------------
__global__ __launch_bounds__(256) void prep_k(const float* __restrict__ W1,
                                              const float* __restrict__ hidden,
                                              const float* __restrict__ b1,
                                              const void*  __restrict__ maskv,
                                              u16*   __restrict__ Wb,
                                              float* __restrict__ hv,
                                              int*   __restrict__ sidx,
                                              int*   __restrict__ cnt,
                                              float* __restrict__ scores) {
    const int bx = blockIdx.x, t = threadIdx.x;
    const int wid = t >> 6, lane = t & 63;
    __shared__ int sflag[4];

    if (bx < 512) {
        // pack W1_enc to bf16, swizzled: chunk gc -> (gc&~7)|((gc&7)^(n&7))
        const int i = bx * 256 + t;                    // 16B-out-chunk id, 0..131071
        const int n = i >> 7, gc = i & 127;
        const int p = (gc & ~7) | ((gc & 7) ^ (n & 7));
        const float4 v0 = *(const float4*)(W1 + (size_t)n * 2048 + gc * 8);
        const float4 v1 = *(const float4*)(W1 + (size_t)n * 2048 + gc * 8 + 4);
        uint4 o; o.x = pk2(v0.x, v0.y); o.y = pk2(v0.z, v0.w);
        o.z = pk2(v1.x, v1.y); o.w = pk2(v1.z, v1.w);
        *(uint4*)(Wb + (size_t)n * 1024 + p * 8) = o;
    } else if (bx < 768) {
        // hv[b][h] = hidden[b,:]·W1_hid[h,:] + b1[h]
        const int h = (bx - 512) * 4 + wid;
        const float4* wrow = (const float4*)(W1 + (size_t)h * 2048 + 1024);
        float4 w[4];
#pragma unroll
        for (int q = 0; q < 4; q++) w[q] = wrow[lane + 64 * q];
        for (int b = 0; b < 32; b++) {
            const float4* hb = (const float4*)(hidden + (size_t)b * 1024);
            float p = 0.f;
#pragma unroll
            for (int q = 0; q < 4; q++) {
                float4 x = hb[lane + 64 * q];
                p = fmaf(w[q].x, x.x, fmaf(w[q].y, x.y, fmaf(w[q].z, x.z, fmaf(w[q].w, x.w, p))));
            }
#pragma unroll
            for (int off = 1; off < 64; off <<= 1) p += __shfl_xor(p, off);
            if (lane == 0) hv[(size_t)b * 1024 + h] = p + b1[h];
        }
    } else if (bx < 776) {
        // mask dtype detect + per-batch stable compaction of unmasked s
        const u32* mw = (const u32*)maskv;
        int f = 0;
#pragma unroll
        for (int j = 0; j < 32; j++) f |= (mw[t * 32 + j] > 1u) ? 1 : 0;
        const int anyf = __any(f);
        if (lane == 0) sflag[wid] = anyf;
        __syncthreads();
        const int bytemode = sflag[0] | sflag[1] | sflag[2] | sflag[3];

        const int b = (bx - 768) * 4 + wid;
        int base = 0;
        for (int c = 0; c < 16; c++) {
            const int s = c * 64 + lane;
            int m;
            if (bytemode) m = ((const unsigned char*)maskv)[(size_t)b * 1024 + s];
            else          m = ((const int*)maskv)[(size_t)b * 1024 + s];
            const u64 bal = __ballot(m == 0);
            if (m == 0) {
                const int off = (int)__popcll(bal & ((1ull << lane) - 1ull));
                sidx[(size_t)b * 1024 + base + off] = s;
            }
            base += (int)__popcll(bal);
        }
        if (lane == 0) cnt[b] = base;
        for (int j = base + lane; j < 1024; j += 64) sidx[(size_t)b * 1024 + j] = 0;
    } else {
        // zero scores
        const int i = (bx - 776) * 256 + t;
        ((float4*)scores)[i] = make_float4(0.f, 0.f, 0.f, 0.f);
    }
}

// ---------------- gather-convert compacted enc rows to bf16, SWIZZLED, 128-padded ----------------
// 8192 blocks, XCD-aligned to the gemm's batch->XCD map. 4 rows per block.
__global__ __launch_bounds__(256) void conv_k(const float* __restrict__ enc,
                                              const int* __restrict__ sidx,
                                              const int* __restrict__ cnt,
                                              u16* __restrict__ encC) {
    const int bid = blockIdx.x, t = threadIdx.x;
    const int xcd = bid & 7, w = bid >> 3;             // w 0..1023
    const int b = xcd * 4 + (w >> 8);                  // batches 4X..4X+3 on XCD X
    const int j0 = (w & 255) * 4;
    const int c = cnt[b];
    if (j0 >= ((c + 127) & ~127)) return;              // pad to 128-row tiles
    const int gc = t >> 1, h = t & 1;                  // 16B chunk, half
#pragma unroll
    for (int r = 0; r < 4; r++) {
        const int j = j0 + r;
        const int s = (j < c) ? sidx[(size_t)b * 1024 + j] : 0;
        const float4 v = ((const float4*)(enc + ((size_t)s * 32 + b) * 1024))[t];
        const int p = (gc & ~7) | ((gc & 7) ^ (j & 7));    // swizzle within K-segment
        uint2 o; o.x = pk2(v.x, v.y); o.y = pk2(v.z, v.w);
        *(uint2*)(encC + ((size_t)b * 1024 + j) * 1024 + p * 8 + h * 4) = o;
    }
}

// ---------------- GEMM: 128x128 tile, 512 thr / 8 waves, full occupancy, swizzled LDS ----------------
// waves (wr 0..3 x wc 0..1); per-wave out 32x64 (acc[2][4]) — r13's proven fragment shape.
__global__ __launch_bounds__(512, 8) void gemm_w(
    const u16* __restrict__ encC,       // [32][1024][1024] bf16, swizzled rows
    const u16* __restrict__ Wb,         // [1024][1024] bf16, swizzled rows
    const int* __restrict__ sidx,
    const int* __restrict__ cnt,
    const float* __restrict__ hv,
    const float* __restrict__ W2,
    float*      __restrict__ scores)    // [32][1024] f32, pre-zeroed, atomics
{
    __shared__ u16 As[128 * BK];        // 16 KB
    __shared__ u16 Bs[128 * BK];        // 16 KB  (32 KB -> wave-capped 4 blocks/CU)

    const int tid = threadIdx.x;
    const int bid = blockIdx.x;         // 2048 blocks
    // XCD map (bijective, 2048 = 8*256): batches [4X,4X+4) on XCD X (conv-aligned);
    // 8 nt of one (b,mt) strip stay on one XCD.
    const int xcd = bid & 7, idx = bid >> 3;           // idx 0..255
    const int strip = xcd * 32 + (idx >> 3);           // 0..255 = b*8+mt
    const int nt = idx & 7;
    const int b = strip >> 3, mt = strip & 7;
    const int c = cnt[b];
    if (mt * 128 >= c) return;

    // staging: chunk cix = j*512+tid -> row = j*64 + (tid>>3), c16 = tid&7; LINEAR
    const int srow = tid >> 3, sc16 = tid & 7;         // srow 0..63
    const u16* asrc = encC + ((size_t)b * 1024 + mt * 128 + srow) * 1024 + sc16 * 8;
    const u16* bsrc = Wb + ((size_t)(nt * 128) + srow) * 1024 + sc16 * 8;

    const int wid = tid >> 6, lane = tid & 63;
    const int wr = wid >> 1, wc = wid & 1;             // wr 0..3, wc 0..1
    const int lhi = lane >> 4, llo = lane & 15;

    f32x4 acc[2][4] = {};

    for (int kt = 0; kt < NKT; kt++) {
        const size_t ko = (size_t)kt * 64;
#pragma unroll
        for (int j = 0; j < 2; j++)                    // A: 1024 chunks
            gload_lds16(asrc + ko + (size_t)j * 64 * 1024, &As[(j * 512 + tid) * 8]);
#pragma unroll
        for (int j = 0; j < 2; j++)                    // B: 1024 chunks
            gload_lds16(bsrc + ko + (size_t)j * 64 * 1024, &Bs[(j * 512 + tid) * 8]);
        __syncthreads();
#pragma unroll
        for (int kk = 0; kk < 2; kk++) {
            s16x8 af[2], bfr[4];
#pragma unroll
            for (int f = 0; f < 2; f++) {
                const int row = wr * 32 + f * 16 + llo;
                const int ph = (kk * 4 + lhi) ^ (llo & 7);
                af[f] = *(const s16x8*)&As[row * BK + ph * 8];
            }
#pragma unroll
            for (int f = 0; f < 4; f++) {
                const int row = wc * 64 + f * 16 + llo;
                const int ph = (kk * 4 + lhi) ^ (llo & 7);
                bfr[f] = *(const s16x8*)&Bs[row * BK + ph * 8];
            }
#pragma unroll
            for (int fi = 0; fi < 2; fi++)
#pragma unroll
                for (int fj = 0; fj < 4; fj++)
                    acc[fi][fj] = __builtin_amdgcn_mfma_f32_16x16x32_bf16(af[fi], bfr[fj], acc[fi][fj], 0, 0, 0);
        }
        __syncthreads();
    }

    // epilogue: tanh(acc + hv) · w2, reduce over this wave's 64 n-cols, scatter-atomic
    // (2 wc-waves accumulate into the same score row via atomicAdd)
    const float* hvb = hv + (size_t)b * 1024;
    float hvv[4], w2v[4];
#pragma unroll
    for (int fj = 0; fj < 4; fj++) {
        const int n = nt * 128 + wc * 64 + fj * 16 + llo;
        hvv[fj] = hvb[n];
        w2v[fj] = W2[n];
    }
#pragma unroll
    for (int fi = 0; fi < 2; fi++) {
#pragma unroll
        for (int r = 0; r < 4; r++) {
            float sum = 0.f;
#pragma unroll
            for (int fj = 0; fj < 4; fj++) {
                const float x = acc[fi][fj][r] + hvv[fj];
                const float e = __expf(2.f * x);
                const float t = 1.f - 2.f / (e + 1.f);   // tanh(x)
                sum = fmaf(t, w2v[fj], sum);
            }
            sum += __shfl_xor(sum, 1);
            sum += __shfl_xor(sum, 2);
            sum += __shfl_xor(sum, 4);
            sum += __shfl_xor(sum, 8);
            if (llo == 0) {
                const int j = mt * 128 + wr * 32 + fi * 16 + lhi * 4 + r;
                if (j < c) {
                    const int s = sidx[(size_t)b * 1024 + j];
                    atomicAdd(&scores[(size_t)b * 1024 + s], sum);
                }
            }
        }
    }
}

// ---------------- masked softmax per row b, mask dtype auto-detected ----------------
__global__ __launch_bounds__(256) void softmax_k(const float* __restrict__ scores,
                                                 const void* __restrict__ maskv,
                                                 float* __restrict__ out) {
    const int b = blockIdx.x, t = threadIdx.x;
    const int wid = t >> 6, lane = t & 63;
    const u32* mw = (const u32*)maskv;
    int f = 0;
#pragma unroll
    for (int j = 0; j < 32; j++) f |= (mw[t * 32 + j] > 1u) ? 1 : 0;
    __shared__ int sflag[4];
    const int anyf = __any(f);
    if (lane == 0) sflag[wid] = anyf;
    __syncthreads();
    const int bytemode = sflag[0] | sflag[1] | sflag[2] | sflag[3];

    int m0, m1, m2, m3;
    if (bytemode) {
        const uchar4 mk = ((const uchar4*)((const unsigned char*)maskv + (size_t)b * 1024))[t];
        m0 = mk.x; m1 = mk.y; m2 = mk.z; m3 = mk.w;
    } else {
        const int4 mk = ((const int4*)((const int*)maskv + (size_t)b * 1024))[t];
        m0 = mk.x; m1 = mk.y; m2 = mk.z; m3 = mk.w;
    }
    const float4 sc = ((const float4*)(scores + (size_t)b * 1024))[t];
    const float v0 = m0 ? -1e30f : sc.x;
    const float v1 = m1 ? -1e30f : sc.y;
    const float v2 = m2 ? -1e30f : sc.z;
    const float v3 = m3 ? -1e30f : sc.w;
    float mx = fmaxf(fmaxf(v0, v1), fmaxf(v2, v3));
#pragma unroll
    for (int off = 1; off < 64; off <<= 1) mx = fmaxf(mx, __shfl_xor(mx, off));
    __shared__ float redm[4], reds[4];
    if (lane == 0) redm[wid] = mx;
    __syncthreads();
    mx = fmaxf(fmaxf(redm[0], redm[1]), fmaxf(redm[2], redm[3]));
    const float e0 = m0 ? 0.f : __expf(v0 - mx);
    const float e1 = m1 ? 0.f : __expf(v1 - mx);
    const float e2 = m2 ? 0.f : __expf(v2 - mx);
    const float e3 = m3 ? 0.f : __expf(v3 - mx);
    float s = e0 + e1 + e2 + e3;
#pragma unroll
    for (int off = 1; off < 64; off <<= 1) s += __shfl_xor(s, off);
    if (lane == 0) reds[wid] = s;
    __syncthreads();
    s = reds[0] + reds[1] + reds[2] + reds[3];
    const float inv = 1.f / s;
    float4 o; o.x = e0 * inv; o.y = e1 * inv; o.z = e2 * inv; o.w = e3 * inv;
    ((float4*)(out + (size_t)b * 1024))[t] = o;
}

extern "C" void kernel_launch(void* const* d_in, const int* in_sizes, int n_in,
                              void* d_out, int out_size, void* d_ws, size_t ws_size,
                              hipStream_t stream) {
    const float* hidden = (const float*)d_in[0];
    const float* enc    = (const float*)d_in[1];           // (S,B,H_IN) f32
    const void*  mask   = d_in[2];
    const float* W1 = (const float*)d_in[3];               // (H, H_IN+H) f32
    const float* b1 = (const float*)d_in[4];
    const float* W2 = (const float*)d_in[5];
    float* out = (float*)d_out;

    char* ws = (char*)d_ws;
    float* ws_scores = (float*)ws;                          // 128 KB
    float* ws_hv     = (float*)(ws + (128u << 10));         // 128 KB
    u16*   ws_Wb     = (u16*)(ws + (256u << 10));           // 2 MB (swizzled)
    int*   ws_cnt    = (int*)(ws + (2304u << 10));          // 128 B
    int*   ws_sidx   = (int*)(ws + (2432u << 10));          // 128 KB
    u16*   ws_encC   = (u16*)(ws + (4096u << 10));          // 64 MB (swizzled rows)

    prep_k<<<808, 256, 0, stream>>>(W1, hidden, b1, mask, ws_Wb, ws_hv, ws_sidx, ws_cnt, ws_scores);
    conv_k<<<8192, 256, 0, stream>>>(enc, ws_sidx, ws_cnt, ws_encC);
    gemm_w<<<2048, 512, 0, stream>>>(ws_encC, ws_Wb, ws_sidx, ws_cnt, ws_hv, W2, ws_scores);
    softmax_k<<<32, 256, 0, stream>>>(ws_scores, mask, out);
}

// Round 18
// 95.796 us; speedup vs baseline: 1.2921x; 1.1336x over previous
//
#include <hip/hip_runtime.h>
#include <hip/hip_bf16.h>
#include <cstdint>

// Problem: B=32, S=1024, H_IN=1024, H=1024
// scores[b,s] = sum_h tanh( enc[b,s,:]·W1_enc[h,:] + hidden[b,:]·W1_hid[h,:] + b1[h] ) * W2[h]
// out[b,0,s] = softmax_s( mask ? -inf : scores )    (b2 is softmax-shift-invariant)
//
// Round 18 (4 launches) = r13 (best measured: 101.5us) + de-atomic epilogue:
// gemm stores per-(nt,wc) partials (16 slots, single writer per slot — r9-proven
// pattern) instead of 262k XCD-colocated atomicAdds; softmax sums 16 partials;
// scores zeroing removed (masked slots discarded, unmasked fully overwritten).
// prep/conv/gemm otherwise byte-identical to r13 (swizzled sources, linear
// gload_lds staging, XOR ds_read, 64x128 tile, 6 blocks/CU).

#define BK 64
#define NKT 16

typedef short  s16x8 __attribute__((ext_vector_type(8)));
typedef float  f32x4 __attribute__((ext_vector_type(4)));
typedef unsigned int u32;
typedef unsigned short u16;
typedef unsigned long long u64;

__device__ static inline u32 f2bf(float f) {            // f32 -> bf16 (RNE)
    u32 u = __float_as_uint(f);
    return (u + 0x7fffu + ((u >> 16) & 1u)) >> 16;
}
__device__ static inline u32 pk2(float a, float b) {
    return f2bf(a) | (f2bf(b) << 16);
}

__device__ static inline void gload_lds16(const void* g, void* l) {
    __builtin_amdgcn_global_load_lds(
        (const __attribute__((address_space(1))) u32*)g,
        (__attribute__((address_space(3))) u32*)l, 16, 0, 0);
}

// ---------------- prep: pack W1_enc (SWIZZLED) + hv + mask compaction ----------------
__global__ __launch_bounds__(256) void prep_k(const float* __restrict__ W1,
                                              const float* __restrict__ hidden,
                                              const float* __restrict__ b1,
                                              const void*  __restrict__ maskv,
                                              u16*   __restrict__ Wb,
                                              float* __restrict__ hv,
                                              int*   __restrict__ sidx,
                                              int*   __restrict__ cnt) {
    const int bx = blockIdx.x, t = threadIdx.x;
    const int wid = t >> 6, lane = t & 63;
    __shared__ int sflag[4];

    if (bx < 512) {
        // pack W1_enc to bf16, swizzled: chunk gc -> (gc&~7)|((gc&7)^(n&7))
        const int i = bx * 256 + t;                    // 16B-out-chunk id, 0..131071
        const int n = i >> 7, gc = i & 127;
        const int p = (gc & ~7) | ((gc & 7) ^ (n & 7));
        const float4 v0 = *(const float4*)(W1 + (size_t)n * 2048 + gc * 8);
        const float4 v1 = *(const float4*)(W1 + (size_t)n * 2048 + gc * 8 + 4);
        uint4 o; o.x = pk2(v0.x, v0.y); o.y = pk2(v0.z, v0.w);
        o.z = pk2(v1.x, v1.y); o.w = pk2(v1.z, v1.w);
        *(uint4*)(Wb + (size_t)n * 1024 + p * 8) = o;
    } else if (bx < 768) {
        // hv[b][h] = hidden[b,:]·W1_hid[h,:] + b1[h]
        const int h = (bx - 512) * 4 + wid;
        const float4* wrow = (const float4*)(W1 + (size_t)h * 2048 + 1024);
        float4 w[4];
#pragma unroll
        for (int q = 0; q < 4; q++) w[q] = wrow[lane + 64 * q];
        for (int b = 0; b < 32; b++) {
            const float4* hb = (const float4*)(hidden + (size_t)b * 1024);
            float p = 0.f;
#pragma unroll
            for (int q = 0; q < 4; q++) {
                float4 x = hb[lane + 64 * q];
                p = fmaf(w[q].x, x.x, fmaf(w[q].y, x.y, fmaf(w[q].z, x.z, fmaf(w[q].w, x.w, p))));
            }
#pragma unroll
            for (int off = 1; off < 64; off <<= 1) p += __shfl_xor(p, off);
            if (lane == 0) hv[(size_t)b * 1024 + h] = p + b1[h];
        }
    } else {
        // mask dtype detect + per-batch stable compaction of unmasked s
        const u32* mw = (const u32*)maskv;
        int f = 0;
#pragma unroll
        for (int j = 0; j < 32; j++) f |= (mw[t * 32 + j] > 1u) ? 1 : 0;
        const int anyf = __any(f);
        if (lane == 0) sflag[wid] = anyf;
        __syncthreads();
        const int bytemode = sflag[0] | sflag[1] | sflag[2] | sflag[3];

        const int b = (bx - 768) * 4 + wid;
        int base = 0;
        for (int c = 0; c < 16; c++) {
            const int s = c * 64 + lane;
            int m;
            if (bytemode) m = ((const unsigned char*)maskv)[(size_t)b * 1024 + s];
            else          m = ((const int*)maskv)[(size_t)b * 1024 + s];
            const u64 bal = __ballot(m == 0);
            if (m == 0) {
                const int off = (int)__popcll(bal & ((1ull << lane) - 1ull));
                sidx[(size_t)b * 1024 + base + off] = s;
            }
            base += (int)__popcll(bal);
        }
        if (lane == 0) cnt[b] = base;
        for (int j = base + lane; j < 1024; j += 64) sidx[(size_t)b * 1024 + j] = 0;
    }
}

// ---------------- gather-convert compacted enc rows to bf16, SWIZZLED, 128-padded ----------------
// 8192 blocks, XCD-aligned to the gemm's batch->XCD map. 4 rows per block.
__global__ __launch_bounds__(256) void conv_k(const float* __restrict__ enc,
                                              const int* __restrict__ sidx,
                                              const int* __restrict__ cnt,
                                              u16* __restrict__ encC) {
    const int bid = blockIdx.x, t = threadIdx.x;
    const int xcd = bid & 7, w = bid >> 3;             // w 0..1023
    const int b = xcd * 4 + (w >> 8);                  // batches 4X..4X+3 on XCD X
    const int j0 = (w & 255) * 4;
    const int c = cnt[b];
    if (j0 >= ((c + 127) & ~127)) return;              // pad to 128 (>= any 64-tile range)
    const int gc = t >> 1, h = t & 1;                  // 16B chunk, half
#pragma unroll
    for (int r = 0; r < 4; r++) {
        const int j = j0 + r;
        const int s = (j < c) ? sidx[(size_t)b * 1024 + j] : 0;
        const float4 v = ((const float4*)(enc + ((size_t)s * 32 + b) * 1024))[t];
        const int p = (gc & ~7) | ((gc & 7) ^ (j & 7));    // swizzle within K-segment
        uint2 o; o.x = pk2(v.x, v.y); o.y = pk2(v.z, v.w);
        *(uint2*)(encC + ((size_t)b * 1024 + j) * 1024 + p * 8 + h * 4) = o;
    }
}

// ---------------- GEMM: 64x128 tile, 6 blocks/CU, 2-barrier, swizzled LDS, partial stores ----------------
// 256 threads = 4 waves (wr 0..1 x wc 0..1); per-wave out 32x64 (acc[2][4]).
__global__ __launch_bounds__(256, 6) void gemm_s(
    const u16* __restrict__ encC,       // [32][1024][1024] bf16, swizzled rows
    const u16* __restrict__ Wb,         // [1024][1024] bf16, swizzled rows
    const int* __restrict__ sidx,
    const int* __restrict__ cnt,
    const float* __restrict__ hv,
    const float* __restrict__ W2,
    float*      __restrict__ scores_p)  // [16][32][1024] f32 partials (slot nt*2+wc)
{
    __shared__ u16 As[64 * BK];         // 8 KB
    __shared__ u16 Bs[128 * BK];        // 16 KB   (24 KB -> 6 blocks/CU)

    const int tid = threadIdx.x;
    const int bid = blockIdx.x;         // 4096 blocks
    // XCD map (bijective, 4096 = 8*512): batches [4X,4X+4) on XCD X (conv-aligned);
    // 8 nt of one (b,mt) strip stay on one XCD.
    const int xcd = bid & 7, idx = bid >> 3;           // idx 0..511
    const int strip = xcd * 64 + (idx >> 3);           // 0..511 = b*16+mt
    const int nt = idx & 7;
    const int b = strip >> 4, mt = strip & 15;
    const int c = cnt[b];
    if (mt * 64 >= c) return;

    // staging: chunk idx -> row = chunk>>3, c16 = chunk&7 (16B units); LINEAR
    const int srow = tid >> 3, sc16 = tid & 7;         // srow 0..31
    const u16* asrc = encC + ((size_t)b * 1024 + mt * 64 + srow) * 1024 + sc16 * 8;
    const u16* bsrc = Wb + ((size_t)(nt * 128) + srow) * 1024 + sc16 * 8;

    const int wid = tid >> 6, lane = tid & 63;
    const int wr = wid >> 1, wc = wid & 1;
    const int lhi = lane >> 4, llo = lane & 15;

    f32x4 acc[2][4] = {};

    for (int kt = 0; kt < NKT; kt++) {
        const size_t ko = (size_t)kt * 64;
#pragma unroll
        for (int j = 0; j < 2; j++)                    // A: 512 chunks
            gload_lds16(asrc + ko + (size_t)j * 32 * 1024, &As[(j * 256 + tid) * 8]);
#pragma unroll
        for (int j = 0; j < 4; j++)                    // B: 1024 chunks
            gload_lds16(bsrc + ko + (size_t)j * 32 * 1024, &Bs[(j * 256 + tid) * 8]);
        __syncthreads();
#pragma unroll
        for (int kk = 0; kk < 2; kk++) {
            s16x8 af[2], bfr[4];
#pragma unroll
            for (int f = 0; f < 2; f++) {
                const int row = wr * 32 + f * 16 + llo;
                const int ph = (kk * 4 + lhi) ^ (llo & 7);
                af[f] = *(const s16x8*)&As[row * BK + ph * 8];
            }
#pragma unroll
            for (int f = 0; f < 4; f++) {
                const int row = wc * 64 + f * 16 + llo;
                const int ph = (kk * 4 + lhi) ^ (llo & 7);
                bfr[f] = *(const s16x8*)&Bs[row * BK + ph * 8];
            }
#pragma unroll
            for (int fi = 0; fi < 2; fi++)
#pragma unroll
                for (int fj = 0; fj < 4; fj++)
                    acc[fi][fj] = __builtin_amdgcn_mfma_f32_16x16x32_bf16(af[fi], bfr[fj], acc[fi][fj], 0, 0, 0);
        }
        __syncthreads();
    }

    // epilogue: tanh(acc + hv) · w2, reduce over this wave's 64 n-cols,
    // store per-(nt,wc) partial — exactly one writer per (b,s,slot), no atomics.
    const float* hvb = hv + (size_t)b * 1024;
    float* outp = scores_p + (((size_t)nt * 2 + wc) * 32 + b) * 1024;
    float hvv[4], w2v[4];
#pragma unroll
    for (int fj = 0; fj < 4; fj++) {
        const int n = nt * 128 + wc * 64 + fj * 16 + llo;
        hvv[fj] = hvb[n];
        w2v[fj] = W2[n];
    }
#pragma unroll
    for (int fi = 0; fi < 2; fi++) {
#pragma unroll
        for (int r = 0; r < 4; r++) {
            float sum = 0.f;
#pragma unroll
            for (int fj = 0; fj < 4; fj++) {
                const float x = acc[fi][fj][r] + hvv[fj];
                const float e = __expf(2.f * x);
                const float t = 1.f - 2.f / (e + 1.f);   // tanh(x)
                sum = fmaf(t, w2v[fj], sum);
            }
            sum += __shfl_xor(sum, 1);
            sum += __shfl_xor(sum, 2);
            sum += __shfl_xor(sum, 4);
            sum += __shfl_xor(sum, 8);
            if (llo == 0) {
                const int j = mt * 64 + wr * 32 + fi * 16 + lhi * 4 + r;
                if (j < c) {
                    outp[sidx[(size_t)b * 1024 + j]] = sum;
                }
            }
        }
    }
}

// ---------------- masked softmax per row b: sum 16 per-(nt,wc) partials ----------------
__global__ __launch_bounds__(256) void softmax_k(const float* __restrict__ scores_p,
                                                 const void* __restrict__ maskv,
                                                 float* __restrict__ out) {
    const int b = blockIdx.x, t = threadIdx.x;
    const int wid = t >> 6, lane = t & 63;
    const u32* mw = (const u32*)maskv;
    int f = 0;
#pragma unroll
    for (int j = 0; j < 32; j++) f |= (mw[t * 32 + j] > 1u) ? 1 : 0;
    __shared__ int sflag[4];
    const int anyf = __any(f);
    if (lane == 0) sflag[wid] = anyf;
    __syncthreads();
    const int bytemode = sflag[0] | sflag[1] | sflag[2] | sflag[3];

    int m0, m1, m2, m3;
    if (bytemode) {
        const uchar4 mk = ((const uchar4*)((const unsigned char*)maskv + (size_t)b * 1024))[t];
        m0 = mk.x; m1 = mk.y; m2 = mk.z; m3 = mk.w;
    } else {
        const int4 mk = ((const int4*)((const int*)maskv + (size_t)b * 1024))[t];
        m0 = mk.x; m1 = mk.y; m2 = mk.z; m3 = mk.w;
    }
    // sum 16 per-(nt,wc) partials (masked lanes' garbage discarded below)
    float4 sc = make_float4(0.f, 0.f, 0.f, 0.f);
#pragma unroll
    for (int p = 0; p < 16; p++) {
        const float4 v = ((const float4*)(scores_p + ((size_t)p * 32 + b) * 1024))[t];
        sc.x += v.x; sc.y += v.y; sc.z += v.z; sc.w += v.w;
    }
    const float v0 = m0 ? -1e30f : sc.x;
    const float v1 = m1 ? -1e30f : sc.y;
    const float v2 = m2 ? -1e30f : sc.z;
    const float v3 = m3 ? -1e30f : sc.w;
    float mx = fmaxf(fmaxf(v0, v1), fmaxf(v2, v3));
#pragma unroll
    for (int off = 1; off < 64; off <<= 1) mx = fmaxf(mx, __shfl_xor(mx, off));
    __shared__ float redm[4], reds[4];
    if (lane == 0) redm[wid] = mx;
    __syncthreads();
    mx = fmaxf(fmaxf(redm[0], redm[1]), fmaxf(redm[2], redm[3]));
    const float e0 = m0 ? 0.f : __expf(v0 - mx);
    const float e1 = m1 ? 0.f : __expf(v1 - mx);
    const float e2 = m2 ? 0.f : __expf(v2 - mx);
    const float e3 = m3 ? 0.f : __expf(v3 - mx);
    float s = e0 + e1 + e2 + e3;
#pragma unroll
    for (int off = 1; off < 64; off <<= 1) s += __shfl_xor(s, off);
    if (lane == 0) reds[wid] = s;
    __syncthreads();
    s = reds[0] + reds[1] + reds[2] + reds[3];
    const float inv = 1.f / s;
    float4 o; o.x = e0 * inv; o.y = e1 * inv; o.z = e2 * inv; o.w = e3 * inv;
    ((float4*)(out + (size_t)b * 1024))[t] = o;
}

extern "C" void kernel_launch(void* const* d_in, const int* in_sizes, int n_in,
                              void* d_out, int out_size, void* d_ws, size_t ws_size,
                              hipStream_t stream) {
    const float* hidden = (const float*)d_in[0];
    const float* enc    = (const float*)d_in[1];           // (S,B,H_IN) f32
    const void*  mask   = d_in[2];
    const float* W1 = (const float*)d_in[3];               // (H, H_IN+H) f32
    const float* b1 = (const float*)d_in[4];
    const float* W2 = (const float*)d_in[5];
    float* out = (float*)d_out;

    char* ws = (char*)d_ws;
    float* ws_scores_p = (float*)ws;                        // 2 MB  (16x32x1024 f32)
    float* ws_hv       = (float*)(ws + (2048u << 10));      // 128 KB
    u16*   ws_Wb       = (u16*)(ws + (2176u << 10));        // 2 MB (swizzled)
    int*   ws_cnt      = (int*)(ws + (4224u << 10));        // 128 B
    int*   ws_sidx     = (int*)(ws + (4352u << 10));        // 128 KB
    u16*   ws_encC     = (u16*)(ws + (5120u << 10));        // 64 MB (swizzled rows)

    prep_k<<<776, 256, 0, stream>>>(W1, hidden, b1, mask, ws_Wb, ws_hv, ws_sidx, ws_cnt);
    conv_k<<<8192, 256, 0, stream>>>(enc, ws_sidx, ws_cnt, ws_encC);
    gemm_s<<<4096, 256, 0, stream>>>(ws_encC, ws_Wb, ws_sidx, ws_cnt, ws_hv, W2, ws_scores_p);
    softmax_k<<<32, 256, 0, stream>>>(ws_scores_p, mask, out);
}